// Round 1
// baseline (892.191 us; speedup 1.0000x reference)
//
#include <hip/hip_runtime.h>

// ScatterND add-reduction:  out = data.clone(); out[idx[k]] += updates[k]
// N=1048576, D=128, K=262144 (derived from in_sizes at launch).
// Strategy: inverse map in workspace, then single fused streaming pass so
// every HBM byte is touched exactly once (~1.16 GiB total traffic).

// --- kernel 1: inv[i] = -1 for all rows (vectorized int4) ------------------
__global__ void inv_init_kernel(int4* __restrict__ inv4, int n4) {
    int i = blockIdx.x * blockDim.x + threadIdx.x;
    if (i < n4) inv4[i] = make_int4(-1, -1, -1, -1);
}

// --- kernel 2: inv[idx[k]] = k  (indices unique, no atomics needed) --------
__global__ void inv_scatter_kernel(const int* __restrict__ idx,
                                   int* __restrict__ inv, int K) {
    int k = blockIdx.x * blockDim.x + threadIdx.x;
    if (k < K) inv[idx[k]] = k;
}

// --- kernel 3: fused copy+add. One float4 per thread. ----------------------
// dvec = D/4 float4s per row.
__global__ void fused_scatter_add_kernel(const float4* __restrict__ data,
                                         const float4* __restrict__ upd,
                                         const int* __restrict__ inv,
                                         float4* __restrict__ out,
                                         int nvec, unsigned dvec) {
    int i = blockIdx.x * blockDim.x + threadIdx.x;
    if (i >= nvec) return;
    unsigned row  = (unsigned)i / dvec;
    unsigned lane = (unsigned)i - row * dvec;
    float4 v = data[i];
    int k = inv[row];
    if (k >= 0) {
        float4 u = upd[(long long)k * dvec + lane];
        v.x += u.x; v.y += u.y; v.z += u.z; v.w += u.w;
    }
    out[i] = v;
}

// --- fallback path (if ws too small): copy then unique-index RMW -----------
__global__ void copy_kernel(const float4* __restrict__ src,
                            float4* __restrict__ dst, int nvec) {
    int i = blockIdx.x * blockDim.x + threadIdx.x;
    if (i < nvec) dst[i] = src[i];
}

__global__ void rmw_add_kernel(const float4* __restrict__ upd,
                               const int* __restrict__ idx,
                               float4* __restrict__ out,
                               int kvec, unsigned dvec) {
    int i = blockIdx.x * blockDim.x + threadIdx.x;
    if (i >= kvec) return;
    unsigned k    = (unsigned)i / dvec;
    unsigned lane = (unsigned)i - k * dvec;
    long long off = (long long)idx[k] * dvec + lane;
    float4 u = upd[i];
    float4 v = out[off];
    v.x += u.x; v.y += u.y; v.z += u.z; v.w += u.w;
    out[off] = v;
}

extern "C" void kernel_launch(void* const* d_in, const int* in_sizes, int n_in,
                              void* d_out, int out_size, void* d_ws, size_t ws_size,
                              hipStream_t stream) {
    const float* data = (const float*)d_in[0];
    const int*   idx  = (const int*)d_in[1];
    const float* upd  = (const float*)d_in[2];
    float* out = (float*)d_out;

    const int K = in_sizes[1];                 // 262144
    const int D = in_sizes[2] / K;             // 128
    const int N = in_sizes[0] / D;             // 1048576
    const unsigned dvec = (unsigned)(D / 4);   // 32 float4 per row
    const int nvec = in_sizes[0] / 4;          // total float4 in out
    const int kvec = in_sizes[2] / 4;          // total float4 in updates

    const int BS = 256;

    if (ws_size >= (size_t)N * sizeof(int)) {
        int* inv = (int*)d_ws;
        int n4 = N / 4;
        inv_init_kernel<<<(n4 + BS - 1) / BS, BS, 0, stream>>>((int4*)inv, n4);
        inv_scatter_kernel<<<(K + BS - 1) / BS, BS, 0, stream>>>(idx, inv, K);
        fused_scatter_add_kernel<<<(nvec + BS - 1) / BS, BS, 0, stream>>>(
            (const float4*)data, (const float4*)upd, inv, (float4*)out, nvec, dvec);
    } else {
        copy_kernel<<<(nvec + BS - 1) / BS, BS, 0, stream>>>(
            (const float4*)data, (float4*)out, nvec);
        rmw_add_kernel<<<(kvec + BS - 1) / BS, BS, 0, stream>>>(
            (const float4*)upd, idx, (float4*)out, kvec, dvec);
    }
}